// Round 4
// baseline (629.596 us; speedup 1.0000x reference)
//
#include <hip/hip_runtime.h>
#include <stdint.h>

typedef unsigned short u16;
typedef __attribute__((ext_vector_type(4))) float f32x4;
typedef __attribute__((ext_vector_type(16))) float f32x16;
typedef __attribute__((ext_vector_type(8))) short s16x8;
typedef __attribute__((ext_vector_type(8))) __bf16 bf16x8;
typedef __attribute__((ext_vector_type(8))) unsigned short u16x8;
typedef __attribute__((ext_vector_type(4))) unsigned short u16x4;
typedef __attribute__((ext_vector_type(4))) uint32_t u32x4;
typedef __attribute__((ext_vector_type(2))) uint32_t u32x2;

__device__ __forceinline__ f32x4 mfma16(s16x8 a, s16x8 b, f32x4 c) {
  return __builtin_amdgcn_mfma_f32_16x16x32_bf16(
      __builtin_bit_cast(bf16x8, a), __builtin_bit_cast(bf16x8, b), c, 0, 0, 0);
}
__device__ __forceinline__ f32x16 mfma32(s16x8 a, s16x8 b, f32x16 c) {
  return __builtin_amdgcn_mfma_f32_32x32x16_bf16(
      __builtin_bit_cast(bf16x8, a), __builtin_bit_cast(bf16x8, b), c, 0, 0, 0);
}

__device__ __forceinline__ void gl_lds16(const u16* g, u16* l) {
  __builtin_amdgcn_global_load_lds(
      (const __attribute__((address_space(1))) void*)g,
      (__attribute__((address_space(3))) void*)l, 16, 0, 0);
}

__device__ __forceinline__ u16 bf16rne(float f) {
  uint32_t u = __builtin_bit_cast(uint32_t, f);
  u += 0x7fffu + ((u >> 16) & 1u);
  return (u16)(u >> 16);
}

// ---------------- cast x (f32 -> bf16), grid-stride ----------------
__global__ void cast_x_kernel(const float* __restrict__ x, u16* __restrict__ xb) {
  const size_t total = (size_t)16384 * 2048;
  const size_t stride = (size_t)2048 * 256 * 8;
  for (size_t i = ((size_t)blockIdx.x * 256 + threadIdx.x) * 8; i < total; i += stride) {
    f32x4 a = *(const f32x4*)(x + i);
    f32x4 b = *(const f32x4*)(x + i + 4);
    u16x8 o;
#pragma unroll
    for (int j = 0; j < 4; ++j) { o[j] = bf16rne(a[j]); o[4 + j] = bf16rne(b[j]); }
    *(u16x8*)(xb + i) = o;
  }
}

// ------- cast W -> Wt[768][2048] bf16 (WQ rows pre-scaled by scale*log2e) -------
__global__ void cast_w_kernel(const float* __restrict__ WQ, const float* __restrict__ WK,
                              const float* __restrict__ WV, u16* __restrict__ Wt, float qscale) {
  int i = blockIdx.x * 256 + threadIdx.x;  // 768*2048 threads
  int r = i >> 11, k = i & 2047;
  int sel = r >> 8, c = r & 255;
  const float* W = (sel == 0) ? WQ : (sel == 1) ? WK : WV;
  float v = W[(size_t)k * 256 + c];
  if (sel == 0) v *= qscale;
  Wt[i] = bf16rne(v);
}

// ---------------- QKV projection GEMM: [16384,2048] x [2048,768] ----------------
// XCD-swizzled; V written transposed: Vt[b][col][s].
__global__ __launch_bounds__(256) void proj_gemm(const u16* __restrict__ xb, const u16* __restrict__ Wt,
                                                 u16* __restrict__ Qb, u16* __restrict__ Kb,
                                                 u16* __restrict__ Vt) {
  const int bid = blockIdx.x;             // 768 blocks
  const int xcd = bid & 7, j = bid >> 3;  // j in 0..95
  const int m0 = (xcd * 16 + (j / 6)) * 128;
  const int n0 = (j % 6) * 128;
  const int tid = threadIdx.x, lane = tid & 63, w = tid >> 6;
  const int ln = lane & 15, quad = lane >> 4;
  const int wm = w & 1, wn = w >> 1;
  __shared__ __align__(16) u16 As[128 * 32];
  __shared__ __align__(16) u16 Bs[128 * 32];
  f32x4 acc[4][4];
#pragma unroll
  for (int i = 0; i < 4; ++i)
#pragma unroll
    for (int jj = 0; jj < 4; ++jj) acc[i][jj] = f32x4{0.f, 0.f, 0.f, 0.f};

  for (int kk = 0; kk < 2048; kk += 32) {
    __syncthreads();
#pragma unroll
    for (int i = 0; i < 2; ++i) {
      int p = tid + i * 256;
      int row = p >> 2, cg = (p & 3) ^ (row & 3);
      gl_lds16(xb + (size_t)(m0 + row) * 2048 + kk + cg * 8, As + (size_t)(p - lane) * 8);
      gl_lds16(Wt + (size_t)(n0 + row) * 2048 + kk + cg * 8, Bs + (size_t)(p - lane) * 8);
    }
    __syncthreads();
    s16x8 a[4];
#pragma unroll
    for (int mt = 0; mt < 4; ++mt) {
      int r = wm * 64 + mt * 16 + ln;
      a[mt] = *(const s16x8*)(As + r * 32 + ((quad ^ (r & 3)) * 8));
    }
#pragma unroll
    for (int nt = 0; nt < 4; ++nt) {
      int r = wn * 64 + nt * 16 + ln;
      s16x8 bf = *(const s16x8*)(Bs + r * 32 + ((quad ^ (r & 3)) * 8));
#pragma unroll
      for (int mt = 0; mt < 4; ++mt) acc[mt][nt] = mfma16(a[mt], bf, acc[mt][nt]);
    }
  }
#pragma unroll
  for (int mt = 0; mt < 4; ++mt)
#pragma unroll
    for (int nt = 0; nt < 4; ++nt) {
      int row0 = m0 + wm * 64 + mt * 16 + quad * 4;
      int col = n0 + wn * 64 + nt * 16 + ln;
      int sel = col >> 8, c = col & 255;
      u16x4 vv;
#pragma unroll
      for (int jj = 0; jj < 4; ++jj) vv[jj] = bf16rne(acc[mt][nt][jj]);
      if (sel == 2) {
        int b = row0 >> 12, s = row0 & 4095;
        *(u16x4*)(Vt + (size_t)b * 1048576 + (size_t)c * 4096 + s) = vv;
      } else {
        u16* dst = (sel == 0) ? Qb : Kb;
#pragma unroll
        for (int jj = 0; jj < 4; ++jj) dst[(size_t)(row0 + jj) * 256 + c] = vv[jj];
      }
    }
}

// ---------------- lambda scalar ----------------
__global__ void lam_kernel(const float* __restrict__ lq1, const float* __restrict__ lq2,
                           const float* __restrict__ lk1, const float* __restrict__ lk2,
                           float* __restrict__ lamp) {
  int t = threadIdx.x;  // 64 threads
  float d1 = lq1[t] * lk1[t] + lq1[t + 64] * lk1[t + 64];
  float d2 = lq2[t] * lk2[t] + lq2[t + 64] * lk2[t + 64];
#pragma unroll
  for (int off = 32; off; off >>= 1) {
    d1 += __shfl_xor(d1, off);
    d2 += __shfl_xor(d2, off);
  }
  if (t == 0) *lamp = expf(d1) + expf(d2) + (0.8f - 0.6f * expf(-3.6f));
}

// ------- fused flash attention: 64 q-rows/block, 8 waves, dbuf staging -------
// 256 blocks (xcd-pinned batch), 1 block/CU, 2 waves/SIMD. 8 waves =
// (map m, key-sub kt, q-slice qh). One barrier per iter (drains stage(t),
// which had all of compute(t-1) behind it); stage(t+1) into the other 64KB
// buffer; compute(t). VALU-trimmed softmax: native __bf16 casts (compiler
// emits v_cvt_pk_bf16_f32, same RNE rounding as bf16rne) + permlane32_swap
// half-exchange. T5 setprio(1) around both MFMA clusters.
__global__ __launch_bounds__(512, 2) void attn_kernel(const u16* __restrict__ Qb,
                                                      const u16* __restrict__ Kb,
                                                      const u16* __restrict__ Vt,
                                                      const float* __restrict__ lamp,
                                                      float* __restrict__ out) {
  const int bid = blockIdx.x;
  const int xcd = bid & 7;
  const int b = xcd >> 1;
  const int qt = ((bid >> 3) << 1) + (xcd & 1);  // 0..63, q rows qt*64..+64
  const int tid = threadIdx.x, lane = tid & 63, w = tid >> 6;
  const int l5 = lane & 31, lh = lane >> 5;
  const int m = w & 1, kt = (w >> 1) & 1, qh = w >> 2;

  // dbuf: two 64KB buffers [Ks 32KB | Vs 32KB]; epilogue overlays the lot.
  __shared__ __align__(16) char smem[134144];
  float* buf0 = (float*)smem;            // epilogue: map0 O^T [256][65]
  float* buf1 = (float*)(smem + 66560);  // epilogue: map1 O^T [256][65]
  float* ls = (float*)(smem + 133120);   // l partials [w][32]

  const u16* Kg0 = Kb + ((size_t)b * 4096) * 256;
  const u16* Vg0 = Vt + (size_t)b * 1048576;

  auto stage = [&](int kb, char* base) {
    u16* Ks = (u16*)base;
    u16* Vs = (u16*)(base + 32768);
#pragma unroll
    for (int i = 0; i < 4; ++i) {
      int p = tid + i * 512;
      int row = p >> 5, c = p & 31;
      int cg = (c & 16) | ((c ^ row) & 15);
      gl_lds16(Kg0 + (size_t)(kb + row) * 256 + cg * 8, Ks + (size_t)(p - lane) * 8);
    }
#pragma unroll
    for (int i = 0; i < 4; ++i) {
      int p = tid + i * 512;
      int row = p >> 3, c = p & 7;
      int cg = c ^ (row & 7);
      gl_lds16(Vg0 + (size_t)row * 4096 + kb + cg * 8, Vs + (size_t)(p - lane) * 8);
    }
  };

  // kick off tile 0 staging before anything else
  stage(0, smem);

  // Q^T B-frags: B[k=d][n=q]: lane q = l5 within slice qh, d = s*16 + lh*8 + j
  s16x8 bq[8];
  {
    const u16* qp =
        Qb + ((size_t)(b * 4096 + qt * 64 + qh * 32 + l5)) * 256 + m * 128 + lh * 8;
#pragma unroll
    for (int s = 0; s < 8; ++s) bq[s] = *(const s16x8*)(qp + s * 16);
  }

  f32x16 O[8];
#pragma unroll
  for (int ct = 0; ct < 8; ++ct)
#pragma unroll
    for (int r = 0; r < 16; ++r) O[ct][r] = 0.f;
  float l_run = 0.f;

  for (int t = 0; t < 64; ++t) {
    __syncthreads();  // stage(t) complete (vmcnt drain); compute(t-1) reads done
    if (t + 1 < 64) stage((t + 1) * 64, smem + ((t + 1) & 1) * 65536);

    char* base = smem + (t & 1) * 65536;
    u16* Ks = (u16*)base;
    u16* Vs = (u16*)(base + 32768);

    // S^T[32 keys][32 q] = K . Q^T for (map m, keys kt*32..+32); two chains
    f32x16 Sa, Sb;
#pragma unroll
    for (int r = 0; r < 16; ++r) { Sa[r] = 0.f; Sb[r] = 0.f; }
    __builtin_amdgcn_s_setprio(1);
#pragma unroll
    for (int s = 0; s < 8; s += 2) {
      int row = kt * 32 + l5;
      int c0 = m * 16 + s * 2 + lh;
      int c1 = m * 16 + (s + 1) * 2 + lh;
      s16x8 a0 = *(const s16x8*)(Ks + row * 256 + (((c0 & 16) | ((c0 ^ row) & 15))) * 8);
      s16x8 a1 = *(const s16x8*)(Ks + row * 256 + (((c1 & 16) | ((c1 ^ row) & 15))) * 8);
      Sa = mfma32(a0, bq[s], Sa);
      Sb = mfma32(a1, bq[s + 1], Sb);
    }
    __builtin_amdgcn_s_setprio(0);

    // pre-read all V frags into regs (PV becomes pure-reg; hides LDS latency)
    s16x8 vfr0[8], vfr1[8];
#pragma unroll
    for (int ct = 0; ct < 8; ++ct) {
      int row = ct * 32 + l5;
      int c0v = (kt * 32) / 8 + lh;
      int c1v = (kt * 32 + 16) / 8 + lh;
      vfr0[ct] = *(const s16x8*)(Vs + row * 64 + ((c0v ^ (row & 7)) * 8));
      vfr1[ct] = *(const s16x8*)(Vs + row * 64 + ((c1v ^ (row & 7)) * 8));
    }

    // p = exp2(s); accumulate l; pack via native bf16 casts (RNE, same as
    // bf16rne) -> compiler emits v_cvt_pk_bf16_f32: ~40 VALU ops/iter saved
    uint32_t P[8];
#pragma unroll
    for (int d = 0; d < 8; ++d) {
      float p0 = exp2f(Sa[2 * d] + Sb[2 * d]);
      float p1 = exp2f(Sa[2 * d + 1] + Sb[2 * d + 1]);
      l_run += p0 + p1;
      u16 plo = __builtin_bit_cast(u16, (__bf16)p0);
      u16 phi = __builtin_bit_cast(u16, (__bf16)p1);
      P[d] = (uint32_t)plo | ((uint32_t)phi << 16);
    }

    // PV: O^T[256 vcol][32 q] += V^T . P^T ; half-exchange via permlane32_swap:
    // swap(P[4k],P[4k+2]) -> (fd0,fd2), swap(P[4k+1],P[4k+3]) -> (fd1,fd3)
    __builtin_amdgcn_s_setprio(1);
#pragma unroll
    for (int ks = 0; ks < 2; ++ks) {
      u32x2 s02 = __builtin_amdgcn_permlane32_swap(P[ks * 4 + 0], P[ks * 4 + 2], false, false);
      u32x2 s13 = __builtin_amdgcn_permlane32_swap(P[ks * 4 + 1], P[ks * 4 + 3], false, false);
      u32x4 fd;
      fd[0] = s02[0]; fd[1] = s13[0]; fd[2] = s02[1]; fd[3] = s13[1];
      s16x8 pf = __builtin_bit_cast(s16x8, fd);
      if (ks == 0) {
#pragma unroll
        for (int ct = 0; ct < 8; ++ct) O[ct] = mfma32(vfr0[ct], pf, O[ct]);
      } else {
#pragma unroll
        for (int ct = 0; ct < 8; ++ct) O[ct] = mfma32(vfr1[ct], pf, O[ct]);
      }
    }
    __builtin_amdgcn_s_setprio(0);
  }

  // ---------------- epilogue ----------------
  float lam = *lamp;
  l_run += __shfl_xor(l_run, 32);  // fold lh (partner holds other 16 keys)
  __syncthreads();                 // B1: loop reads done; smem becomes buf0/buf1/ls
  if (lane < 32) ls[w * 32 + l5] = l_run;
  float* bufm = m ? buf1 : buf0;
  const int qb0 = qh * 32;
  if (kt == 1) {
#pragma unroll
    for (int ct = 0; ct < 8; ++ct)
#pragma unroll
      for (int r = 0; r < 16; ++r) {
        int vcol = ct * 32 + (r & 3) + 8 * (r >> 2) + 4 * lh;
        bufm[vcol * 65 + qb0 + l5] = O[ct][r];
      }
  }
  __syncthreads();  // B2
  if (kt == 0) {
    float linv = 1.f / (ls[w * 32 + l5] + ls[(w | 2) * 32 + l5]);
#pragma unroll
    for (int ct = 0; ct < 8; ++ct)
#pragma unroll
      for (int r = 0; r < 16; ++r) {
        int vcol = ct * 32 + (r & 3) + 8 * (r >> 2) + 4 * lh;
        bufm[vcol * 65 + qb0 + l5] = (O[ct][r] + bufm[vcol * 65 + qb0 + l5]) * linv;
      }
  }
  __syncthreads();  // B3
  // cooperative write: out[q][col], coalesced; 512 threads = 2 q-halves x 256 cols
  float* og = out + ((size_t)(b * 4096 + qt * 64)) * 256;
  const int col = tid & 255, half = tid >> 8;
#pragma unroll
  for (int j2 = 0; j2 < 32; ++j2) {
    int q = half * 32 + j2;
    float v = buf0[col * 65 + q] - lam * buf1[col * 65 + q];
    og[(size_t)q * 256 + col] = v;
  }
}

extern "C" void kernel_launch(void* const* d_in, const int* in_sizes, int n_in,
                              void* d_out, int out_size, void* d_ws, size_t ws_size,
                              hipStream_t stream) {
  (void)in_sizes; (void)n_in; (void)out_size; (void)ws_size;
  const float* x   = (const float*)d_in[0];
  const float* WQ  = (const float*)d_in[1];
  const float* WK  = (const float*)d_in[2];
  const float* WV  = (const float*)d_in[3];
  const float* lq1 = (const float*)d_in[4];
  const float* lq2 = (const float*)d_in[5];
  const float* lk1 = (const float*)d_in[6];
  const float* lk2 = (const float*)d_in[7];
  float* out = (float*)d_out;

  char* ws = (char*)d_ws;
  u16* xb = (u16*)ws;   ws += (size_t)16384 * 2048 * 2;
  u16* Wt = (u16*)ws;   ws += (size_t)768 * 2048 * 2;
  u16* Qb = (u16*)ws;   ws += (size_t)16384 * 256 * 2;
  u16* Kb = (u16*)ws;   ws += (size_t)16384 * 256 * 2;
  u16* Vt = (u16*)ws;   ws += (size_t)16384 * 256 * 2;  // [b][col 256][s 4096]
  float* lamp = (float*)ws;

  const float qscale = 0.0883883476f * 1.44269504f;  // HEAD_DIM^-0.5 * log2(e)

  hipLaunchKernelGGL(cast_x_kernel, dim3(2048), dim3(256), 0, stream, x, xb);
  hipLaunchKernelGGL(cast_w_kernel, dim3(6144), dim3(256), 0, stream, WQ, WK, WV, Wt, qscale);
  hipLaunchKernelGGL(proj_gemm, dim3(768), dim3(256), 0, stream, xb, Wt, Qb, Kb, Vt);
  hipLaunchKernelGGL(lam_kernel, dim3(1), dim3(64), 0, stream, lq1, lq2, lk1, lk2, lamp);
  hipLaunchKernelGGL(attn_kernel, dim3(256), dim3(512), 0, stream, Qb, Kb, Vt, lamp, out);
}

// Round 5
// 401.124 us; speedup vs baseline: 1.5696x; 1.5696x over previous
//
#include <hip/hip_runtime.h>
#include <stdint.h>

typedef unsigned short u16;
typedef __attribute__((ext_vector_type(4))) float f32x4;
typedef __attribute__((ext_vector_type(16))) float f32x16;
typedef __attribute__((ext_vector_type(8))) short s16x8;
typedef __attribute__((ext_vector_type(8))) __bf16 bf16x8;
typedef __attribute__((ext_vector_type(8))) unsigned short u16x8;
typedef __attribute__((ext_vector_type(4))) unsigned short u16x4;
typedef __attribute__((ext_vector_type(4))) uint32_t u32x4;
typedef __attribute__((ext_vector_type(2))) uint32_t u32x2;

__device__ __forceinline__ f32x4 mfma16(s16x8 a, s16x8 b, f32x4 c) {
  return __builtin_amdgcn_mfma_f32_16x16x32_bf16(
      __builtin_bit_cast(bf16x8, a), __builtin_bit_cast(bf16x8, b), c, 0, 0, 0);
}
__device__ __forceinline__ f32x16 mfma32(s16x8 a, s16x8 b, f32x16 c) {
  return __builtin_amdgcn_mfma_f32_32x32x16_bf16(
      __builtin_bit_cast(bf16x8, a), __builtin_bit_cast(bf16x8, b), c, 0, 0, 0);
}

__device__ __forceinline__ void gl_lds16(const u16* g, u16* l) {
  __builtin_amdgcn_global_load_lds(
      (const __attribute__((address_space(1))) void*)g,
      (__attribute__((address_space(3))) void*)l, 16, 0, 0);
}

__device__ __forceinline__ u16 bf16rne(float f) {
  uint32_t u = __builtin_bit_cast(uint32_t, f);
  u += 0x7fffu + ((u >> 16) & 1u);
  return (u16)(u >> 16);
}

// ---------------- cast x (f32 -> bf16), grid-stride ----------------
__global__ void cast_x_kernel(const float* __restrict__ x, u16* __restrict__ xb) {
  const size_t total = (size_t)16384 * 2048;
  const size_t stride = (size_t)2048 * 256 * 8;
  for (size_t i = ((size_t)blockIdx.x * 256 + threadIdx.x) * 8; i < total; i += stride) {
    f32x4 a = *(const f32x4*)(x + i);
    f32x4 b = *(const f32x4*)(x + i + 4);
    u16x8 o;
#pragma unroll
    for (int j = 0; j < 4; ++j) { o[j] = bf16rne(a[j]); o[4 + j] = bf16rne(b[j]); }
    *(u16x8*)(xb + i) = o;
  }
}

// ------- cast W -> Wt[768][2048] bf16 (WQ rows pre-scaled by scale*log2e) -------
__global__ void cast_w_kernel(const float* __restrict__ WQ, const float* __restrict__ WK,
                              const float* __restrict__ WV, u16* __restrict__ Wt, float qscale) {
  int i = blockIdx.x * 256 + threadIdx.x;  // 768*2048 threads
  int r = i >> 11, k = i & 2047;
  int sel = r >> 8, c = r & 255;
  const float* W = (sel == 0) ? WQ : (sel == 1) ? WK : WV;
  float v = W[(size_t)k * 256 + c];
  if (sel == 0) v *= qscale;
  Wt[i] = bf16rne(v);
}

// ---------------- QKV projection GEMM: [16384,2048] x [2048,768] ----------------
// XCD-swizzled; V written transposed: Vt[b][col][s].
__global__ __launch_bounds__(256) void proj_gemm(const u16* __restrict__ xb, const u16* __restrict__ Wt,
                                                 u16* __restrict__ Qb, u16* __restrict__ Kb,
                                                 u16* __restrict__ Vt) {
  const int bid = blockIdx.x;             // 768 blocks
  const int xcd = bid & 7, j = bid >> 3;  // j in 0..95
  const int m0 = (xcd * 16 + (j / 6)) * 128;
  const int n0 = (j % 6) * 128;
  const int tid = threadIdx.x, lane = tid & 63, w = tid >> 6;
  const int ln = lane & 15, quad = lane >> 4;
  const int wm = w & 1, wn = w >> 1;
  __shared__ __align__(16) u16 As[128 * 32];
  __shared__ __align__(16) u16 Bs[128 * 32];
  f32x4 acc[4][4];
#pragma unroll
  for (int i = 0; i < 4; ++i)
#pragma unroll
    for (int jj = 0; jj < 4; ++jj) acc[i][jj] = f32x4{0.f, 0.f, 0.f, 0.f};

  for (int kk = 0; kk < 2048; kk += 32) {
    __syncthreads();
#pragma unroll
    for (int i = 0; i < 2; ++i) {
      int p = tid + i * 256;
      int row = p >> 2, cg = (p & 3) ^ (row & 3);
      gl_lds16(xb + (size_t)(m0 + row) * 2048 + kk + cg * 8, As + (size_t)(p - lane) * 8);
      gl_lds16(Wt + (size_t)(n0 + row) * 2048 + kk + cg * 8, Bs + (size_t)(p - lane) * 8);
    }
    __syncthreads();
    s16x8 a[4];
#pragma unroll
    for (int mt = 0; mt < 4; ++mt) {
      int r = wm * 64 + mt * 16 + ln;
      a[mt] = *(const s16x8*)(As + r * 32 + ((quad ^ (r & 3)) * 8));
    }
#pragma unroll
    for (int nt = 0; nt < 4; ++nt) {
      int r = wn * 64 + nt * 16 + ln;
      s16x8 bf = *(const s16x8*)(Bs + r * 32 + ((quad ^ (r & 3)) * 8));
#pragma unroll
      for (int mt = 0; mt < 4; ++mt) acc[mt][nt] = mfma16(a[mt], bf, acc[mt][nt]);
    }
  }
#pragma unroll
  for (int mt = 0; mt < 4; ++mt)
#pragma unroll
    for (int nt = 0; nt < 4; ++nt) {
      int row0 = m0 + wm * 64 + mt * 16 + quad * 4;
      int col = n0 + wn * 64 + nt * 16 + ln;
      int sel = col >> 8, c = col & 255;
      u16x4 vv;
#pragma unroll
      for (int jj = 0; jj < 4; ++jj) vv[jj] = bf16rne(acc[mt][nt][jj]);
      if (sel == 2) {
        int b = row0 >> 12, s = row0 & 4095;
        *(u16x4*)(Vt + (size_t)b * 1048576 + (size_t)c * 4096 + s) = vv;
      } else {
        u16* dst = (sel == 0) ? Qb : Kb;
#pragma unroll
        for (int jj = 0; jj < 4; ++jj) dst[(size_t)(row0 + jj) * 256 + c] = vv[jj];
      }
    }
}

// ---------------- lambda scalar ----------------
__global__ void lam_kernel(const float* __restrict__ lq1, const float* __restrict__ lq2,
                           const float* __restrict__ lk1, const float* __restrict__ lk2,
                           float* __restrict__ lamp) {
  int t = threadIdx.x;  // 64 threads
  float d1 = lq1[t] * lk1[t] + lq1[t + 64] * lk1[t + 64];
  float d2 = lq2[t] * lk2[t] + lq2[t + 64] * lk2[t + 64];
#pragma unroll
  for (int off = 32; off; off >>= 1) {
    d1 += __shfl_xor(d1, off);
    d2 += __shfl_xor(d2, off);
  }
  if (t == 0) *lamp = expf(d1) + expf(d2) + (0.8f - 0.6f * expf(-3.6f));
}

// ------- fused flash attention: 64 q-rows/block, 8 waves, dbuf staging -------
// 256 blocks (xcd-pinned batch), 1 block/CU, 2 waves/SIMD. 8 waves =
// (map m, key-sub kt, q-slice qh). One barrier per iter (drains stage(t),
// which had all of compute(t-1) behind it); stage(t+1) into the other 64KB
// buffer; compute(t). Round-3 proven structure; NO setprio (R4 showed it
// triggers scratch spills in this zero-headroom kernel). One change vs R3:
// exp2f -> __builtin_amdgcn_exp2f (raw v_exp_f32, drops __ocml wrapper VALU).
__global__ __launch_bounds__(512, 2) void attn_kernel(const u16* __restrict__ Qb,
                                                      const u16* __restrict__ Kb,
                                                      const u16* __restrict__ Vt,
                                                      const float* __restrict__ lamp,
                                                      float* __restrict__ out) {
  const int bid = blockIdx.x;
  const int xcd = bid & 7;
  const int b = xcd >> 1;
  const int qt = ((bid >> 3) << 1) + (xcd & 1);  // 0..63, q rows qt*64..+64
  const int tid = threadIdx.x, lane = tid & 63, w = tid >> 6;
  const int l5 = lane & 31, lh = lane >> 5;
  const int m = w & 1, kt = (w >> 1) & 1, qh = w >> 2;

  // dbuf: two 64KB buffers [Ks 32KB | Vs 32KB]; epilogue overlays the lot.
  __shared__ __align__(16) char smem[134144];
  float* buf0 = (float*)smem;            // epilogue: map0 O^T [256][65]
  float* buf1 = (float*)(smem + 66560);  // epilogue: map1 O^T [256][65]
  float* ls = (float*)(smem + 133120);   // l partials [w][32]

  const u16* Kg0 = Kb + ((size_t)b * 4096) * 256;
  const u16* Vg0 = Vt + (size_t)b * 1048576;

  auto stage = [&](int kb, char* base) {
    u16* Ks = (u16*)base;
    u16* Vs = (u16*)(base + 32768);
#pragma unroll
    for (int i = 0; i < 4; ++i) {
      int p = tid + i * 512;
      int row = p >> 5, c = p & 31;
      int cg = (c & 16) | ((c ^ row) & 15);
      gl_lds16(Kg0 + (size_t)(kb + row) * 256 + cg * 8, Ks + (size_t)(p - lane) * 8);
    }
#pragma unroll
    for (int i = 0; i < 4; ++i) {
      int p = tid + i * 512;
      int row = p >> 3, c = p & 7;
      int cg = c ^ (row & 7);
      gl_lds16(Vg0 + (size_t)row * 4096 + kb + cg * 8, Vs + (size_t)(p - lane) * 8);
    }
  };

  // kick off tile 0 staging before anything else
  stage(0, smem);

  // Q^T B-frags: B[k=d][n=q]: lane q = l5 within slice qh, d = s*16 + lh*8 + j
  s16x8 bq[8];
  {
    const u16* qp =
        Qb + ((size_t)(b * 4096 + qt * 64 + qh * 32 + l5)) * 256 + m * 128 + lh * 8;
#pragma unroll
    for (int s = 0; s < 8; ++s) bq[s] = *(const s16x8*)(qp + s * 16);
  }

  f32x16 O[8];
#pragma unroll
  for (int ct = 0; ct < 8; ++ct)
#pragma unroll
    for (int r = 0; r < 16; ++r) O[ct][r] = 0.f;
  float l_run = 0.f;

  for (int t = 0; t < 64; ++t) {
    __syncthreads();  // stage(t) complete (vmcnt drain); compute(t-1) reads done
    if (t + 1 < 64) stage((t + 1) * 64, smem + ((t + 1) & 1) * 65536);

    char* base = smem + (t & 1) * 65536;
    u16* Ks = (u16*)base;
    u16* Vs = (u16*)(base + 32768);

    // S^T[32 keys][32 q] = K . Q^T for (map m, keys kt*32..+32); two chains
    f32x16 Sa, Sb;
#pragma unroll
    for (int r = 0; r < 16; ++r) { Sa[r] = 0.f; Sb[r] = 0.f; }
#pragma unroll
    for (int s = 0; s < 8; s += 2) {
      int row = kt * 32 + l5;
      int c0 = m * 16 + s * 2 + lh;
      int c1 = m * 16 + (s + 1) * 2 + lh;
      s16x8 a0 = *(const s16x8*)(Ks + row * 256 + (((c0 & 16) | ((c0 ^ row) & 15))) * 8);
      s16x8 a1 = *(const s16x8*)(Ks + row * 256 + (((c1 & 16) | ((c1 ^ row) & 15))) * 8);
      Sa = mfma32(a0, bq[s], Sa);
      Sb = mfma32(a1, bq[s + 1], Sb);
    }

    // pre-read all V frags into regs (PV becomes pure-reg; hides LDS latency)
    s16x8 vfr0[8], vfr1[8];
#pragma unroll
    for (int ct = 0; ct < 8; ++ct) {
      int row = ct * 32 + l5;
      int c0v = (kt * 32) / 8 + lh;
      int c1v = (kt * 32 + 16) / 8 + lh;
      vfr0[ct] = *(const s16x8*)(Vs + row * 64 + ((c0v ^ (row & 7)) * 8));
      vfr1[ct] = *(const s16x8*)(Vs + row * 64 + ((c1v ^ (row & 7)) * 8));
    }

    // p = exp2(s) via raw v_exp_f32; accumulate l; pack to dwords (bf16rne)
    uint32_t P[8];
#pragma unroll
    for (int d = 0; d < 8; ++d) {
      float p0 = __builtin_amdgcn_exp2f(Sa[2 * d] + Sb[2 * d]);
      float p1 = __builtin_amdgcn_exp2f(Sa[2 * d + 1] + Sb[2 * d + 1]);
      l_run += p0 + p1;
      P[d] = (uint32_t)bf16rne(p0) | ((uint32_t)bf16rne(p1) << 16);
    }

    // PV: O^T[256 vcol][32 q] += V^T . P^T ; half-exchange via permlane32_swap:
    // swap(P[4k],P[4k+2]) -> (fd0,fd2), swap(P[4k+1],P[4k+3]) -> (fd1,fd3)
#pragma unroll
    for (int ks = 0; ks < 2; ++ks) {
      u32x2 s02 = __builtin_amdgcn_permlane32_swap(P[ks * 4 + 0], P[ks * 4 + 2], false, false);
      u32x2 s13 = __builtin_amdgcn_permlane32_swap(P[ks * 4 + 1], P[ks * 4 + 3], false, false);
      u32x4 fd;
      fd[0] = s02[0]; fd[1] = s13[0]; fd[2] = s02[1]; fd[3] = s13[1];
      s16x8 pf = __builtin_bit_cast(s16x8, fd);
      if (ks == 0) {
#pragma unroll
        for (int ct = 0; ct < 8; ++ct) O[ct] = mfma32(vfr0[ct], pf, O[ct]);
      } else {
#pragma unroll
        for (int ct = 0; ct < 8; ++ct) O[ct] = mfma32(vfr1[ct], pf, O[ct]);
      }
    }
  }

  // ---------------- epilogue ----------------
  float lam = *lamp;
  l_run += __shfl_xor(l_run, 32);  // fold lh (partner holds other 16 keys)
  __syncthreads();                 // B1: loop reads done; smem becomes buf0/buf1/ls
  if (lane < 32) ls[w * 32 + l5] = l_run;
  float* bufm = m ? buf1 : buf0;
  const int qb0 = qh * 32;
  if (kt == 1) {
#pragma unroll
    for (int ct = 0; ct < 8; ++ct)
#pragma unroll
      for (int r = 0; r < 16; ++r) {
        int vcol = ct * 32 + (r & 3) + 8 * (r >> 2) + 4 * lh;
        bufm[vcol * 65 + qb0 + l5] = O[ct][r];
      }
  }
  __syncthreads();  // B2
  if (kt == 0) {
    float linv = 1.f / (ls[w * 32 + l5] + ls[(w | 2) * 32 + l5]);
#pragma unroll
    for (int ct = 0; ct < 8; ++ct)
#pragma unroll
      for (int r = 0; r < 16; ++r) {
        int vcol = ct * 32 + (r & 3) + 8 * (r >> 2) + 4 * lh;
        bufm[vcol * 65 + qb0 + l5] = (O[ct][r] + bufm[vcol * 65 + qb0 + l5]) * linv;
      }
  }
  __syncthreads();  // B3
  // cooperative write: out[q][col], coalesced; 512 threads = 2 q-halves x 256 cols
  float* og = out + ((size_t)(b * 4096 + qt * 64)) * 256;
  const int col = tid & 255, half = tid >> 8;
#pragma unroll
  for (int j2 = 0; j2 < 32; ++j2) {
    int q = half * 32 + j2;
    float v = buf0[col * 65 + q] - lam * buf1[col * 65 + q];
    og[(size_t)q * 256 + col] = v;
  }
}

extern "C" void kernel_launch(void* const* d_in, const int* in_sizes, int n_in,
                              void* d_out, int out_size, void* d_ws, size_t ws_size,
                              hipStream_t stream) {
  (void)in_sizes; (void)n_in; (void)out_size; (void)ws_size;
  const float* x   = (const float*)d_in[0];
  const float* WQ  = (const float*)d_in[1];
  const float* WK  = (const float*)d_in[2];
  const float* WV  = (const float*)d_in[3];
  const float* lq1 = (const float*)d_in[4];
  const float* lq2 = (const float*)d_in[5];
  const float* lk1 = (const float*)d_in[6];
  const float* lk2 = (const float*)d_in[7];
  float* out = (float*)d_out;

  char* ws = (char*)d_ws;
  u16* xb = (u16*)ws;   ws += (size_t)16384 * 2048 * 2;
  u16* Wt = (u16*)ws;   ws += (size_t)768 * 2048 * 2;
  u16* Qb = (u16*)ws;   ws += (size_t)16384 * 256 * 2;
  u16* Kb = (u16*)ws;   ws += (size_t)16384 * 256 * 2;
  u16* Vt = (u16*)ws;   ws += (size_t)16384 * 256 * 2;  // [b][col 256][s 4096]
  float* lamp = (float*)ws;

  const float qscale = 0.0883883476f * 1.44269504f;  // HEAD_DIM^-0.5 * log2(e)

  hipLaunchKernelGGL(cast_x_kernel, dim3(2048), dim3(256), 0, stream, x, xb);
  hipLaunchKernelGGL(cast_w_kernel, dim3(6144), dim3(256), 0, stream, WQ, WK, WV, Wt, qscale);
  hipLaunchKernelGGL(proj_gemm, dim3(768), dim3(256), 0, stream, xb, Wt, Qb, Kb, Vt);
  hipLaunchKernelGGL(lam_kernel, dim3(1), dim3(64), 0, stream, lq1, lq2, lk1, lk2, lamp);
  hipLaunchKernelGGL(attn_kernel, dim3(256), dim3(512), 0, stream, Qb, Kb, Vt, lamp, out);
}

// Round 6
// 393.525 us; speedup vs baseline: 1.5999x; 1.0193x over previous
//
#include <hip/hip_runtime.h>
#include <stdint.h>

typedef unsigned short u16;
typedef __attribute__((ext_vector_type(4))) float f32x4;
typedef __attribute__((ext_vector_type(16))) float f32x16;
typedef __attribute__((ext_vector_type(8))) short s16x8;
typedef __attribute__((ext_vector_type(8))) __bf16 bf16x8;
typedef __attribute__((ext_vector_type(8))) unsigned short u16x8;
typedef __attribute__((ext_vector_type(4))) unsigned short u16x4;
typedef __attribute__((ext_vector_type(4))) uint32_t u32x4;
typedef __attribute__((ext_vector_type(2))) uint32_t u32x2;

__device__ __forceinline__ f32x4 mfma16(s16x8 a, s16x8 b, f32x4 c) {
  return __builtin_amdgcn_mfma_f32_16x16x32_bf16(
      __builtin_bit_cast(bf16x8, a), __builtin_bit_cast(bf16x8, b), c, 0, 0, 0);
}
__device__ __forceinline__ f32x16 mfma32(s16x8 a, s16x8 b, f32x16 c) {
  return __builtin_amdgcn_mfma_f32_32x32x16_bf16(
      __builtin_bit_cast(bf16x8, a), __builtin_bit_cast(bf16x8, b), c, 0, 0, 0);
}

__device__ __forceinline__ void gl_lds16(const u16* g, u16* l) {
  __builtin_amdgcn_global_load_lds(
      (const __attribute__((address_space(1))) void*)g,
      (__attribute__((address_space(3))) void*)l, 16, 0, 0);
}

__device__ __forceinline__ u16 bf16rne(float f) {
  uint32_t u = __builtin_bit_cast(uint32_t, f);
  u += 0x7fffu + ((u >> 16) & 1u);
  return (u16)(u >> 16);
}

// ---------------- cast x (f32 -> bf16), flat launch (R3-proven) ----------------
__global__ void cast_x_kernel(const float* __restrict__ x, u16* __restrict__ xb) {
  size_t i = ((size_t)blockIdx.x * 256 + threadIdx.x) * 8;
  f32x4 a = *(const f32x4*)(x + i);
  f32x4 b = *(const f32x4*)(x + i + 4);
  u16x8 o;
#pragma unroll
  for (int j = 0; j < 4; ++j) { o[j] = bf16rne(a[j]); o[4 + j] = bf16rne(b[j]); }
  *(u16x8*)(xb + i) = o;
}

// ------- cast W -> Wt[768][2048] bf16 (WQ rows pre-scaled by scale*log2e) -------
__global__ void cast_w_kernel(const float* __restrict__ WQ, const float* __restrict__ WK,
                              const float* __restrict__ WV, u16* __restrict__ Wt, float qscale) {
  int i = blockIdx.x * 256 + threadIdx.x;  // 768*2048 threads
  int r = i >> 11, k = i & 2047;
  int sel = r >> 8, c = r & 255;
  const float* W = (sel == 0) ? WQ : (sel == 1) ? WK : WV;
  float v = W[(size_t)k * 256 + c];
  if (sel == 0) v *= qscale;
  Wt[i] = bf16rne(v);
}

// ---------------- QKV projection GEMM: [16384,2048] x [2048,768] ----------------
// XCD-swizzled; V written transposed: Vt[b][col][s]. Single-barrier dbuf
// staging (same pattern that took attn 183->133): barrier at top of iter t
// drains stage(t) (which overlapped compute(t-1)); then issue stage(t+1) into
// the other buffer; then compute(t). LDS 2x(8KB A + 8KB B) = 32KB.
__global__ __launch_bounds__(256) void proj_gemm(const u16* __restrict__ xb, const u16* __restrict__ Wt,
                                                 u16* __restrict__ Qb, u16* __restrict__ Kb,
                                                 u16* __restrict__ Vt) {
  const int bid = blockIdx.x;             // 768 blocks
  const int xcd = bid & 7, j = bid >> 3;  // j in 0..95
  const int m0 = (xcd * 16 + (j / 6)) * 128;
  const int n0 = (j % 6) * 128;
  const int tid = threadIdx.x, lane = tid & 63, w = tid >> 6;
  const int ln = lane & 15, quad = lane >> 4;
  const int wm = w & 1, wn = w >> 1;
  __shared__ __align__(16) u16 As[2][128 * 32];
  __shared__ __align__(16) u16 Bs[2][128 * 32];
  f32x4 acc[4][4];
#pragma unroll
  for (int i = 0; i < 4; ++i)
#pragma unroll
    for (int jj = 0; jj < 4; ++jj) acc[i][jj] = f32x4{0.f, 0.f, 0.f, 0.f};

  auto stage = [&](int kk, int bi) {
#pragma unroll
    for (int i = 0; i < 2; ++i) {
      int p = tid + i * 256;
      int row = p >> 2, cg = (p & 3) ^ (row & 3);
      gl_lds16(xb + (size_t)(m0 + row) * 2048 + kk + cg * 8, As[bi] + (size_t)(p - lane) * 8);
      gl_lds16(Wt + (size_t)(n0 + row) * 2048 + kk + cg * 8, Bs[bi] + (size_t)(p - lane) * 8);
    }
  };

  stage(0, 0);
  for (int t = 0; t < 64; ++t) {
    __syncthreads();  // stage(t) complete (vmcnt drain); compute(t-1) reads done
    if (t + 1 < 64) stage((t + 1) * 32, (t + 1) & 1);
    const u16* Asb = As[t & 1];
    const u16* Bsb = Bs[t & 1];
    s16x8 a[4];
#pragma unroll
    for (int mt = 0; mt < 4; ++mt) {
      int r = wm * 64 + mt * 16 + ln;
      a[mt] = *(const s16x8*)(Asb + r * 32 + ((quad ^ (r & 3)) * 8));
    }
#pragma unroll
    for (int nt = 0; nt < 4; ++nt) {
      int r = wn * 64 + nt * 16 + ln;
      s16x8 bf = *(const s16x8*)(Bsb + r * 32 + ((quad ^ (r & 3)) * 8));
#pragma unroll
      for (int mt = 0; mt < 4; ++mt) acc[mt][nt] = mfma16(a[mt], bf, acc[mt][nt]);
    }
  }
#pragma unroll
  for (int mt = 0; mt < 4; ++mt)
#pragma unroll
    for (int nt = 0; nt < 4; ++nt) {
      int row0 = m0 + wm * 64 + mt * 16 + quad * 4;
      int col = n0 + wn * 64 + nt * 16 + ln;
      int sel = col >> 8, c = col & 255;
      u16x4 vv;
#pragma unroll
      for (int jj = 0; jj < 4; ++jj) vv[jj] = bf16rne(acc[mt][nt][jj]);
      if (sel == 2) {
        int b = row0 >> 12, s = row0 & 4095;
        *(u16x4*)(Vt + (size_t)b * 1048576 + (size_t)c * 4096 + s) = vv;
      } else {
        u16* dst = (sel == 0) ? Qb : Kb;
#pragma unroll
        for (int jj = 0; jj < 4; ++jj) dst[(size_t)(row0 + jj) * 256 + c] = vv[jj];
      }
    }
}

// ---------------- lambda scalar ----------------
__global__ void lam_kernel(const float* __restrict__ lq1, const float* __restrict__ lq2,
                           const float* __restrict__ lk1, const float* __restrict__ lk2,
                           float* __restrict__ lamp) {
  int t = threadIdx.x;  // 64 threads
  float d1 = lq1[t] * lk1[t] + lq1[t + 64] * lk1[t + 64];
  float d2 = lq2[t] * lk2[t] + lq2[t + 64] * lk2[t + 64];
#pragma unroll
  for (int off = 32; off; off >>= 1) {
    d1 += __shfl_xor(d1, off);
    d2 += __shfl_xor(d2, off);
  }
  if (t == 0) *lamp = expf(d1) + expf(d2) + (0.8f - 0.6f * expf(-3.6f));
}

// ------- fused flash attention: 64 q-rows/block, 8 waves, dbuf staging -------
// R5-proven: 121.4 us, MfmaUtil 38, no spills. Unchanged this round.
__global__ __launch_bounds__(512, 2) void attn_kernel(const u16* __restrict__ Qb,
                                                      const u16* __restrict__ Kb,
                                                      const u16* __restrict__ Vt,
                                                      const float* __restrict__ lamp,
                                                      float* __restrict__ out) {
  const int bid = blockIdx.x;
  const int xcd = bid & 7;
  const int b = xcd >> 1;
  const int qt = ((bid >> 3) << 1) + (xcd & 1);  // 0..63, q rows qt*64..+64
  const int tid = threadIdx.x, lane = tid & 63, w = tid >> 6;
  const int l5 = lane & 31, lh = lane >> 5;
  const int m = w & 1, kt = (w >> 1) & 1, qh = w >> 2;

  // dbuf: two 64KB buffers [Ks 32KB | Vs 32KB]; epilogue overlays the lot.
  __shared__ __align__(16) char smem[134144];
  float* buf0 = (float*)smem;            // epilogue: map0 O^T [256][65]
  float* buf1 = (float*)(smem + 66560);  // epilogue: map1 O^T [256][65]
  float* ls = (float*)(smem + 133120);   // l partials [w][32]

  const u16* Kg0 = Kb + ((size_t)b * 4096) * 256;
  const u16* Vg0 = Vt + (size_t)b * 1048576;

  auto stage = [&](int kb, char* base) {
    u16* Ks = (u16*)base;
    u16* Vs = (u16*)(base + 32768);
#pragma unroll
    for (int i = 0; i < 4; ++i) {
      int p = tid + i * 512;
      int row = p >> 5, c = p & 31;
      int cg = (c & 16) | ((c ^ row) & 15);
      gl_lds16(Kg0 + (size_t)(kb + row) * 256 + cg * 8, Ks + (size_t)(p - lane) * 8);
    }
#pragma unroll
    for (int i = 0; i < 4; ++i) {
      int p = tid + i * 512;
      int row = p >> 3, c = p & 7;
      int cg = c ^ (row & 7);
      gl_lds16(Vg0 + (size_t)row * 4096 + kb + cg * 8, Vs + (size_t)(p - lane) * 8);
    }
  };

  // kick off tile 0 staging before anything else
  stage(0, smem);

  // Q^T B-frags: B[k=d][n=q]: lane q = l5 within slice qh, d = s*16 + lh*8 + j
  s16x8 bq[8];
  {
    const u16* qp =
        Qb + ((size_t)(b * 4096 + qt * 64 + qh * 32 + l5)) * 256 + m * 128 + lh * 8;
#pragma unroll
    for (int s = 0; s < 8; ++s) bq[s] = *(const s16x8*)(qp + s * 16);
  }

  f32x16 O[8];
#pragma unroll
  for (int ct = 0; ct < 8; ++ct)
#pragma unroll
    for (int r = 0; r < 16; ++r) O[ct][r] = 0.f;
  float l_run = 0.f;

  for (int t = 0; t < 64; ++t) {
    __syncthreads();  // stage(t) complete (vmcnt drain); compute(t-1) reads done
    if (t + 1 < 64) stage((t + 1) * 64, smem + ((t + 1) & 1) * 65536);

    char* base = smem + (t & 1) * 65536;
    u16* Ks = (u16*)base;
    u16* Vs = (u16*)(base + 32768);

    // S^T[32 keys][32 q] = K . Q^T for (map m, keys kt*32..+32); two chains
    f32x16 Sa, Sb;
#pragma unroll
    for (int r = 0; r < 16; ++r) { Sa[r] = 0.f; Sb[r] = 0.f; }
#pragma unroll
    for (int s = 0; s < 8; s += 2) {
      int row = kt * 32 + l5;
      int c0 = m * 16 + s * 2 + lh;
      int c1 = m * 16 + (s + 1) * 2 + lh;
      s16x8 a0 = *(const s16x8*)(Ks + row * 256 + (((c0 & 16) | ((c0 ^ row) & 15))) * 8);
      s16x8 a1 = *(const s16x8*)(Ks + row * 256 + (((c1 & 16) | ((c1 ^ row) & 15))) * 8);
      Sa = mfma32(a0, bq[s], Sa);
      Sb = mfma32(a1, bq[s + 1], Sb);
    }

    // pre-read all V frags into regs (PV becomes pure-reg; hides LDS latency)
    s16x8 vfr0[8], vfr1[8];
#pragma unroll
    for (int ct = 0; ct < 8; ++ct) {
      int row = ct * 32 + l5;
      int c0v = (kt * 32) / 8 + lh;
      int c1v = (kt * 32 + 16) / 8 + lh;
      vfr0[ct] = *(const s16x8*)(Vs + row * 64 + ((c0v ^ (row & 7)) * 8));
      vfr1[ct] = *(const s16x8*)(Vs + row * 64 + ((c1v ^ (row & 7)) * 8));
    }

    // p = exp2(s) via raw v_exp_f32; accumulate l; pack to dwords (bf16rne)
    uint32_t P[8];
#pragma unroll
    for (int d = 0; d < 8; ++d) {
      float p0 = __builtin_amdgcn_exp2f(Sa[2 * d] + Sb[2 * d]);
      float p1 = __builtin_amdgcn_exp2f(Sa[2 * d + 1] + Sb[2 * d + 1]);
      l_run += p0 + p1;
      P[d] = (uint32_t)bf16rne(p0) | ((uint32_t)bf16rne(p1) << 16);
    }

    // PV: O^T[256 vcol][32 q] += V^T . P^T ; half-exchange via permlane32_swap:
    // swap(P[4k],P[4k+2]) -> (fd0,fd2), swap(P[4k+1],P[4k+3]) -> (fd1,fd3)
#pragma unroll
    for (int ks = 0; ks < 2; ++ks) {
      u32x2 s02 = __builtin_amdgcn_permlane32_swap(P[ks * 4 + 0], P[ks * 4 + 2], false, false);
      u32x2 s13 = __builtin_amdgcn_permlane32_swap(P[ks * 4 + 1], P[ks * 4 + 3], false, false);
      u32x4 fd;
      fd[0] = s02[0]; fd[1] = s13[0]; fd[2] = s02[1]; fd[3] = s13[1];
      s16x8 pf = __builtin_bit_cast(s16x8, fd);
      if (ks == 0) {
#pragma unroll
        for (int ct = 0; ct < 8; ++ct) O[ct] = mfma32(vfr0[ct], pf, O[ct]);
      } else {
#pragma unroll
        for (int ct = 0; ct < 8; ++ct) O[ct] = mfma32(vfr1[ct], pf, O[ct]);
      }
    }
  }

  // ---------------- epilogue ----------------
  float lam = *lamp;
  l_run += __shfl_xor(l_run, 32);  // fold lh (partner holds other 16 keys)
  __syncthreads();                 // B1: loop reads done; smem becomes buf0/buf1/ls
  if (lane < 32) ls[w * 32 + l5] = l_run;
  float* bufm = m ? buf1 : buf0;
  const int qb0 = qh * 32;
  if (kt == 1) {
#pragma unroll
    for (int ct = 0; ct < 8; ++ct)
#pragma unroll
      for (int r = 0; r < 16; ++r) {
        int vcol = ct * 32 + (r & 3) + 8 * (r >> 2) + 4 * lh;
        bufm[vcol * 65 + qb0 + l5] = O[ct][r];
      }
  }
  __syncthreads();  // B2
  if (kt == 0) {
    float linv = 1.f / (ls[w * 32 + l5] + ls[(w | 2) * 32 + l5]);
#pragma unroll
    for (int ct = 0; ct < 8; ++ct)
#pragma unroll
      for (int r = 0; r < 16; ++r) {
        int vcol = ct * 32 + (r & 3) + 8 * (r >> 2) + 4 * lh;
        bufm[vcol * 65 + qb0 + l5] = (O[ct][r] + bufm[vcol * 65 + qb0 + l5]) * linv;
      }
  }
  __syncthreads();  // B3
  // cooperative write: out[q][col], coalesced; 512 threads = 2 q-halves x 256 cols
  float* og = out + ((size_t)(b * 4096 + qt * 64)) * 256;
  const int col = tid & 255, half = tid >> 8;
#pragma unroll
  for (int j2 = 0; j2 < 32; ++j2) {
    int q = half * 32 + j2;
    float v = buf0[col * 65 + q] - lam * buf1[col * 65 + q];
    og[(size_t)q * 256 + col] = v;
  }
}

extern "C" void kernel_launch(void* const* d_in, const int* in_sizes, int n_in,
                              void* d_out, int out_size, void* d_ws, size_t ws_size,
                              hipStream_t stream) {
  (void)in_sizes; (void)n_in; (void)out_size; (void)ws_size;
  const float* x   = (const float*)d_in[0];
  const float* WQ  = (const float*)d_in[1];
  const float* WK  = (const float*)d_in[2];
  const float* WV  = (const float*)d_in[3];
  const float* lq1 = (const float*)d_in[4];
  const float* lq2 = (const float*)d_in[5];
  const float* lk1 = (const float*)d_in[6];
  const float* lk2 = (const float*)d_in[7];
  float* out = (float*)d_out;

  char* ws = (char*)d_ws;
  u16* xb = (u16*)ws;   ws += (size_t)16384 * 2048 * 2;
  u16* Wt = (u16*)ws;   ws += (size_t)768 * 2048 * 2;
  u16* Qb = (u16*)ws;   ws += (size_t)16384 * 256 * 2;
  u16* Kb = (u16*)ws;   ws += (size_t)16384 * 256 * 2;
  u16* Vt = (u16*)ws;   ws += (size_t)16384 * 256 * 2;  // [b][col 256][s 4096]
  float* lamp = (float*)ws;

  const float qscale = 0.0883883476f * 1.44269504f;  // HEAD_DIM^-0.5 * log2(e)

  hipLaunchKernelGGL(cast_x_kernel, dim3(16384), dim3(256), 0, stream, x, xb);
  hipLaunchKernelGGL(cast_w_kernel, dim3(6144), dim3(256), 0, stream, WQ, WK, WV, Wt, qscale);
  hipLaunchKernelGGL(proj_gemm, dim3(768), dim3(256), 0, stream, xb, Wt, Qb, Kb, Vt);
  hipLaunchKernelGGL(lam_kernel, dim3(1), dim3(64), 0, stream, lq1, lq2, lk1, lk2, lamp);
  hipLaunchKernelGGL(attn_kernel, dim3(256), dim3(512), 0, stream, Qb, Kb, Vt, lamp, out);
}